// Round 6
// baseline (233.078 us; speedup 1.0000x reference)
//
#include <hip/hip_runtime.h>

// Detect (SSD post-process). B=128 P=8732 C=21 TOP_K=200 CONF=0.01 NMS=0.45
//
// R14: ONE kernel (128x1024, one block per batch).
//  phase 0: score own batch, R12-style -- each thread loads its row's 21
//    floats DIRECTLY to registers (no LDS, no barriers; 16 waves streaming)
//    and keeps keys in kreg[9] (i = c*1024+tid mapping, R11/R13-validated).
//  selection: R8-validated round loop (LDS hist -> radix cut [-> bits-45..34
//    refine + clamp] -> ballot compact), scanning kreg.
//  NMS core: rescore -> rank sort + fused decode -> BALLOT kill-mask ->
//    resolve -> output. Kill-mask rewritten from gather form (3 LDS reads per
//    (t,i) pair = ~65K cyc of LDS pipe, the measured 27us hotspot in R13) to
//    ballot form: lane l holds candidate j=64s+l's box in REGISTERS; uniform
//    t-loop does 1 broadcast b128 + 1/4-amortized byte read; kill bits via
//    __ballot; rows staged per-lane (cndmask) and stored 64-at-a-time.
//    Bit-identical kill decisions (same fmaxf/fminf order, area(t) re-derived
//    by the same sub/sub/mul).
//  No workspace, no prep dispatch, conf read once.

typedef unsigned long long u64;

#define BATCH 128
#define NPRIOR 8732
#define NCLS 21
#define TOPK 200
#define T 1024
#define TARGET 256
#define CAP 384
#define NBIN 4096
#define KW 6
#define NCHUNK 9  // ceil(NPRIOR / T); last chunk = 540 rows

__device__ __forceinline__ double exp_fast(double x) {
  // exp for |x| < ~50, rel err < 1e-14. 2^n via exact bit-built multiply.
  // Bit-identical to the version validated R3..R13.
  const double LOG2E = 1.4426950408889634;
  const double LN2_HI = 6.93147180369123816490e-01;
  const double LN2_LO = 1.90821492927058770002e-10;
  double n = rint(x * LOG2E);
  double r = fma(-n, LN2_HI, x);
  r = fma(-n, LN2_LO, r);
  double p = 2.505210838544172e-08;
  p = fma(p, r, 2.755731922398589e-07);
  p = fma(p, r, 2.7557319223985893e-06);
  p = fma(p, r, 2.48015873015873e-05);
  p = fma(p, r, 1.984126984126984e-04);
  p = fma(p, r, 1.388888888888889e-03);
  p = fma(p, r, 8.333333333333333e-03);
  p = fma(p, r, 4.1666666666666664e-02);
  p = fma(p, r, 1.6666666666666666e-01);
  p = fma(p, r, 0.5);
  p = fma(p, r, 1.0);
  p = fma(p, r, 1.0);
  double scale = __longlong_as_double(((long long)(1023 + (int)n)) << 52);
  return p * scale;
}

// Descending cutoff bin over hist[4096] (T=1024 callers): cut[0]=c,
// cut[1]=count in bins>c, cut[2]=count in bins>=c. wtot[16]=grand total.
__device__ __forceinline__ void radix_cut(const int* hist, int tid, int tcap,
                                          int* wtot, int* cut) {
  if (tid == 0) cut[2] = 0;
  const int base = tid * 4;
  const int cs = hist[base] + hist[base + 1] + hist[base + 2] + hist[base + 3];
  const int lane = tid & 63;
  int suf = cs;  // within-wave inclusive suffix sum
#pragma unroll
  for (int off = 1; off < 64; off <<= 1) {
    int v = __shfl_down(suf, off);
    if (lane + off < 64) suf += v;
  }
  if (lane == 0) wtot[tid >> 6] = suf;
  __syncthreads();
  if (tid < 16) {  // wave 0: exclusive suffix over following waves
    int v = wtot[tid];
    int s = v;
#pragma unroll
    for (int off = 1; off < 16; off <<= 1) {
      int o = __shfl_down(s, off);
      if (tid + off < 16) s += o;
    }
    if (tid == 0) wtot[16] = s;  // grand total
    wtot[tid] = s - v;
  }
  __syncthreads();
  const int total = wtot[16];
  if (total > 0) {
    const int target = total < tcap ? total : tcap;
    const int S = suf + wtot[tid >> 6];
    const int Snext = S - cs;
    if (S >= target && Snext < target) {  // unique crossing thread
      int acc = Snext;
      for (int bn = base + 3; bn >= base; --bn) {
        acc += hist[bn];
        if (acc >= target) {
          cut[0] = bn; cut[1] = acc - hist[bn]; cut[2] = acc;
          break;
        }
      }
    }
  }
  __syncthreads();
}

__global__ __launch_bounds__(T) void detect_kernel(
    const float* __restrict__ loc, const float* __restrict__ conf,
    const float* __restrict__ prior, float* __restrict__ out) {
  // DISTINCT shared arrays (no pool carving -> alias analysis works, R8).
  __shared__ int hist[NBIN];        // 16,384 B
  __shared__ u64 buf[CAP];          //  3,072 B (approx keys, unordered)
  __shared__ u64 ebuf[CAP];         //  3,072 B (exact keys)
  __shared__ u64 buf2[CAP];         //  3,072 B (exact, sorted desc)
  __shared__ float4 cbox[CAP];      //  6,144 B (rank-indexed)
  __shared__ float car[CAP];
  __shared__ int ccl[CAP];
  __shared__ __align__(4) unsigned char cclb[CAP];  // class bytes (kill phase)
  __shared__ u64 KILL[CAP * KW];    // 18,432 B
  __shared__ int wtot[17];
  __shared__ int cut1[3], cut2[3];
  __shared__ u64 Ash[KW], KFsh[KW], ACCsh[KW];
  __shared__ float4 abox[TOPK];
  __shared__ float aar[TOPK];
  __shared__ int acl[TOPK];
  __shared__ int sh_cnt, sh_nA;
  // ~59 KB LDS

  const int tid = threadIdx.x;
  const int b = blockIdx.x;
  const float* confb = conf + (long long)b * (NPRIOR * NCLS);
  const float4* loc4 = ((const float4*)loc) + (long long)b * NPRIOR;
  const float4* pr4 = (const float4*)prior;
  float* outb = out + (long long)b * (TOPK * 6);

  // ---- phase 0: score own batch; keys live in registers (no LDS/barriers) --
  u64 kreg[NCHUNK];
#pragma unroll
  for (int c = 0; c < NCHUNK; ++c) {
    const int r = c * T + tid;
    u64 key = 0ULL;
    if (r < NPRIOR) {
      const float* __restrict__ rp = confb + (long long)r * NCLS;
      float cr[NCLS];
#pragma unroll
      for (int j = 0; j < NCLS; ++j) cr[j] = rp[j];  // 21 independent loads
      float m = cr[0];
#pragma unroll
      for (int j = 1; j < NCLS; ++j) m = fmaxf(m, cr[j]);
      float sum = __expf(cr[0] - m);
      float bestr = cr[1];
      float beste = __expf(cr[1] - m);
      sum += beste;
      int bi = 1;
#pragma unroll
      for (int j = 2; j < NCLS; ++j) {
        float rv = cr[j];
        float ej = __expf(rv - m);
        sum += ej;
        if (rv > bestr) { bestr = rv; bi = j; beste = ej; }  // first-idx ties
      }
      float score = __fdividef(beste, sum);  // approx ok: selection only
      if (score > 0.01f) {
        // Scores in (0.01,2): bits 63..58 constant -> bits 57..46 monotone.
        key = ((u64)__float_as_uint(score) << 32) |
              ((u64)(16383 - r) << 10) | (u64)(bi - 1);
      }
    }
    kreg[c] = key;
  }
  if (tid == 0) sh_nA = 0;

  // ---- selection + NMS round loop (R11/R13-validated register scans) ----
  u64 ub = ~0ULL;
  int Mr = 0, total = 0;
  while (true) {
    for (int i = tid; i < NBIN; i += T) hist[i] = 0;
    __syncthreads();
#pragma unroll
    for (int c = 0; c < NCHUNK; ++c) {
      u64 k = kreg[c];
      if (k && k < ub) atomicAdd(&hist[(int)((k >> 46) & 0xFFF)], 1);
    }
    __syncthreads();
    radix_cut(hist, tid, TARGET, wtot, cut1);
    total = wtot[16];
    int M = cut1[2];
    if (M == 0) break;
    const int c1 = cut1[0];
    const int baseA = cut1[1];
    const bool need2 = (M > CAP);
    int c2 = 0;
    if (need2) {  // refine within bin c1 on bits 45..34
      for (int i = tid; i < NBIN; i += T) hist[i] = 0;
      __syncthreads();
#pragma unroll
      for (int c = 0; c < NCHUNK; ++c) {
        u64 k = kreg[c];
        if (k && k < ub && (int)((k >> 46) & 0xFFF) == c1)
          atomicAdd(&hist[(int)((k >> 34) & 0xFFF)], 1);
      }
      __syncthreads();
      const int tcap2 = (total < TARGET ? total : TARGET) - baseA;
      radix_cut(hist, tid, tcap2, wtot, cut2);
      c2 = cut2[0];
      M = baseA + cut2[2];
      if (M > CAP) {  // >=129 keys in one 2^-11 rel f32 window: ~impossible
        int Md = M - hist[c2];
        if (Md > 0) { M = Md; c2 = c2 + 1; } else { M = CAP; }
      }
    }
    if (tid == 0) sh_cnt = 0;
    const u64 ubold = ub;
    ub = need2 ? (((u64)c1 << 46) + ((u64)c2 << 34)) : ((u64)c1 << 46);
    __syncthreads();
    // compact (ballot + 1 LDS atomic/wave); i = c*T+tid mapping as validated.
#pragma unroll
    for (int c = 0; c < NCHUNK; ++c) {
      u64 k = kreg[c];
      bool psel = false;
      if (k && k < ubold) {
        int b1 = (int)((k >> 46) & 0xFFF);
        psel = need2 ? (b1 > c1 || (b1 == c1 && (int)((k >> 34) & 0xFFF) >= c2))
                     : (b1 >= c1);
      }
      u64 mask = __ballot(psel ? 1 : 0);
      if (mask) {
        int lane = tid & 63;
        int leader = __ffsll((unsigned long long)mask) - 1;
        int bpos = 0;
        if (lane == leader) bpos = atomicAdd(&sh_cnt, __popcll(mask));
        bpos = __shfl(bpos, leader);
        if (psel) {
          int pos = bpos + __popcll(mask & ((1ULL << lane) - 1ULL));
          if (pos < CAP) buf[pos] = k;
        }
      }
    }
    __syncthreads();
    Mr = sh_cnt;
    if (Mr > CAP) Mr = CAP;
    if (Mr == 0) break;  // defensive

    // ---- NMS core on buf[0..Mr) ----
    // phase A: exact f64 rescore; loc/prior loads issued early, held in regs
    float4 lreg = make_float4(0.f, 0.f, 0.f, 0.f);
    float4 preg = make_float4(0.f, 0.f, 0.f, 0.f);
    int myp = 0, mycl = 0;
    if (tid < Mr) {
      u64 ak = buf[tid];
      mycl = (int)(ak & 0x1FULL);
      myp = 16383 - (int)((ak >> 10) & 0x3FFFULL);
      lreg = loc4[myp];
      preg = pr4[myp];
      const float* crow = confb + (long long)myp * NCLS;
      float cr[NCLS];
#pragma unroll
      for (int j = 0; j < NCLS; ++j) cr[j] = crow[j];  // independent loads
      double m = (double)cr[0];
#pragma unroll
      for (int j = 1; j < NCLS; ++j) m = fmax(m, (double)cr[j]);
      double sum = 0.0, best = -1.0;
#pragma unroll
      for (int j = 0; j < NCLS; ++j) {
        double ej = exp_fast((double)cr[j] - m);
        sum += ej;
        if (j >= 1 && ej > best) best = ej;  // value only; cl fixed by argmax
      }
      double score = best / sum;
      u64 sb = (u64)__double_as_longlong(score);
      ebuf[tid] = ((sb >> 24) << 24) | ((u64)(16383 - myp) << 10) | (u64)mycl;
    }
    if (tid < KW) { Ash[tid] = 0ULL; KFsh[tid] = 0ULL; }
    __syncthreads();
    const int nA0 = sh_nA;

    // phase B: rank sort on exact keys (unique) + decode own candidate.
    if (tid < Mr) {
      u64 ka = ebuf[tid];
      int ra = 0;
      int i = 0;
      for (; i + 8 <= Mr; i += 8) {
        u64 k0 = ebuf[i], k1 = ebuf[i + 1], k2 = ebuf[i + 2], k3 = ebuf[i + 3];
        u64 k4 = ebuf[i + 4], k5 = ebuf[i + 5], k6 = ebuf[i + 6],
            k7 = ebuf[i + 7];
        ra += (int)(k0 > ka) + (int)(k1 > ka) + (int)(k2 > ka) +
              (int)(k3 > ka) + (int)(k4 > ka) + (int)(k5 > ka) +
              (int)(k6 > ka) + (int)(k7 > ka);
      }
      for (; i < Mr; ++i) ra += (int)(ebuf[i] > ka);
      buf2[ra] = ka;
      // fused decode (bit-identical f64 ops), written at rank position
      double cx = (double)preg.x + (double)lreg.x * 0.1 * (double)preg.z;
      double cy = (double)preg.y + (double)lreg.y * 0.1 * (double)preg.w;
      double w = (double)preg.z * exp_fast((double)lreg.z * 0.2);
      double h = (double)preg.w * exp_fast((double)lreg.w * 0.2);
      float x1 = (float)(cx - w * 0.5), y1 = (float)(cy - h * 0.5);
      float x2 = (float)(cx + w * 0.5), y2 = (float)(cy + h * 0.5);
      cbox[ra] = make_float4(x1, y1, x2, y2);
      car[ra] = (x2 - x1) * (y2 - y1);
      ccl[ra] = mycl;
      cclb[ra] = (unsigned char)mycl;
    }
    __syncthreads();

    // pre-round suppression vs already-accepted (rounds >= 2 only)
    if (nA0 > 0 && tid < Mr) {
      const int t = tid;
      float4 my = cbox[t];
      float mar = car[t];
      int mcl = ccl[t];
      bool sup = false;
      for (int a = 0; a < nA0; ++a) {
        if (acl[a] == mcl) {
          float4 ab = abox[a];
          float ix1 = fmaxf(ab.x, my.x), iy1 = fmaxf(ab.y, my.y);
          float ix2 = fminf(ab.z, my.z), iy2 = fminf(ab.w, my.w);
          float inter = fmaxf(ix2 - ix1, 0.f) * fmaxf(iy2 - iy1, 0.f);
          if (inter > 0.45f * (aar[a] + mar - inter)) sup = true;
        }
      }
      if (sup) atomicOr(&Ash[t >> 6], 1ULL << (t & 63));
    }
    // ---- BALLOT kill-mask: wave s owns seg s; lane l owns j = 64s+l ----
    {
      const int wv = tid >> 6;
      const int lane = tid & 63;
      if (wv < KW) {
        const int s = wv;
        const int j = s * 64 + lane;
        float4 ob = make_float4(0.f, 0.f, 0.f, 0.f);
        float oar = 0.f;
        int ocl = -1;
        if (j < Mr) { ob = cbox[j]; oar = car[j]; ocl = ccl[j]; }
        // process t in tiles of 64; lane l stages the row word for t=t0+l
        for (int t0 = 0; t0 < Mr; t0 += 64) {
          u64 myrow = 0ULL;
          const int tend = (t0 + 64 < Mr) ? (t0 + 64) : Mr;
          unsigned cw = 0;
          for (int t = t0; t < tend; ++t) {
            if ((t & 3) == 0) cw = *(const unsigned*)&cclb[t & ~3];
            const int clt = (int)((cw >> ((t & 3) * 8)) & 0xFF);
            float4 tb = cbox[t];  // broadcast b128
            bool kill = false;
            if (j > t && j < Mr && clt == ocl) {
              float tar = (tb.z - tb.x) * (tb.w - tb.y);  // == car[t] bitwise
              float ix1 = fmaxf(tb.x, ob.x), iy1 = fmaxf(tb.y, ob.y);
              float ix2 = fminf(tb.z, ob.z), iy2 = fminf(tb.w, ob.w);
              float inter = fmaxf(ix2 - ix1, 0.f) * fmaxf(iy2 - iy1, 0.f);
              kill = inter > 0.45f * (tar + oar - inter);
            }
            u64 mm = __ballot(kill ? 1 : 0);
            if (lane == (t - t0)) myrow = mm;  // stage row for t
          }
          // one strided store: lane l writes KILL[(t0+l)*KW + s]
          if (t0 + lane < Mr) KILL[(t0 + lane) * KW + s] = myrow;
          u64 kf = __ballot(myrow != 0ULL);
          if (lane == 0 && kf) atomicOr(&KFsh[t0 >> 6], kf);
        }
      }
    }
    __syncthreads();
    // uniform serial resolve on wave 0 (validated R5..R13)
    if (tid < 64) {
      u64 A0, A1, A2, A3, A4, A5;
      {
        u64 v[KW];
#pragma unroll
        for (int w = 0; w < KW; ++w) {
          int rem = Mr - 64 * w;
          u64 vm =
              (rem >= 64) ? ~0ULL : (rem <= 0 ? 0ULL : ((1ULL << rem) - 1ULL));
          v[w] = vm & ~Ash[w];
        }
        A0 = v[0]; A1 = v[1]; A2 = v[2]; A3 = v[3]; A4 = v[4]; A5 = v[5];
      }
      u64 C0 = 0, C1 = 0, C2 = 0, C3 = 0, C4 = 0, C5 = 0;
      int nacc = nA0;
      bool full = false;
#define KILLUPD(cidx) do { const u64* kc = &KILL[(cidx) * KW];      \
      A0 &= ~kc[0]; A1 &= ~kc[1]; A2 &= ~kc[2];                     \
      A3 &= ~kc[3]; A4 &= ~kc[4]; A5 &= ~kc[5]; } while (0)
#define RESW(w, Aw, Cw) if (!full) {                                \
      const u64 KFw = KFsh[w];                                      \
      int lim = Mr - (w) * 64; if (lim > 64) lim = 64;              \
      for (int q = 0; q < lim; ++q) {                               \
        if ((Aw >> q) & 1ULL) {                                     \
          Cw |= 1ULL << q; ++nacc;                                  \
          if (nacc == TOPK) { full = true; break; }                 \
          if ((KFw >> q) & 1ULL) KILLUPD((w) * 64 + q);             \
        } } }
      RESW(0, A0, C0)
      RESW(1, A1, C1)
      RESW(2, A2, C2)
      RESW(3, A3, C3)
      RESW(4, A4, C4)
      RESW(5, A5, C5)
#undef RESW
#undef KILLUPD
      if (tid == 0) {
        ACCsh[0] = C0; ACCsh[1] = C1; ACCsh[2] = C2;
        ACCsh[3] = C3; ACCsh[4] = C4; ACCsh[5] = C5;
        sh_nA = nacc;
      }
    }
    __syncthreads();
    // lane-parallel output of accepted candidates
    if (tid < Mr) {
      const int t = tid;
      const int w = t >> 6, q = t & 63;
      const u64 accw = ACCsh[w];
      if ((accw >> q) & 1ULL) {
        int rank = nA0;
#pragma unroll
        for (int w2 = 0; w2 < KW; ++w2)
          if (w2 < w) rank += __popcll(ACCsh[w2]);
        rank += __popcll(accw & ((q == 0) ? 0ULL : ((1ULL << q) - 1ULL)));
        float4 bx = cbox[t];
        float sc =
            (float)__longlong_as_double((long long)((buf2[t] >> 24) << 24));
        float* o = outb + rank * 6;
        o[0] = bx.x; o[1] = bx.y; o[2] = bx.z; o[3] = bx.w;
        o[4] = sc; o[5] = (float)ccl[t];
        abox[rank] = bx; aar[rank] = car[t]; acl[rank] = ccl[t];
      }
    }
    __syncthreads();
    if (sh_nA >= TOPK) break;
    if (total - Mr <= 0) break;  // pool exhausted
  }
  __syncthreads();
  // zero-fill rows [nA, TOPK)
  const int nAf = sh_nA;
  for (int i = nAf * 6 + tid; i < TOPK * 6; i += T) outb[i] = 0.0f;
}

extern "C" void kernel_launch(void* const* d_in, const int* in_sizes, int n_in,
                              void* d_out, int out_size, void* d_ws,
                              size_t ws_size, hipStream_t stream) {
  const float* loc = (const float*)d_in[0];    // B*P*4
  const float* conf = (const float*)d_in[1];   // B*P*21
  const float* prior = (const float*)d_in[2];  // P*4
  float* out = (float*)d_out;                  // B*200*6
  (void)d_ws; (void)ws_size;                   // no workspace needed

  detect_kernel<<<BATCH, T, 0, stream>>>(loc, conf, prior, out);
}

// Round 7
// 230.548 us; speedup vs baseline: 1.0110x; 1.0110x over previous
//
#include <hip/hip_runtime.h>

// Detect (SSD post-process). B=128 P=8732 C=21 TOP_K=200 CONF=0.01 NMS=0.45
//
// R15 = R13 two-kernel structure + R14's (validated) ballot kill-mask.
//  prep (4366x256, full chip): one thread = one conf row, 21 floats direct
//    to registers (no LDS, no barrier; R12). Full-chip wave count hides the
//    gather latency (R14 proved 128 blocks cannot: 481 GB/s vs ~2.8 TB/s).
//  selnms (128x1024, one block per batch): batch keys -> kreg[9] (one
//    coalesced pass), R11/R13-validated register-scan selection round loop,
//    NMS core with BALLOT kill-mask (R14-validated bit-identical): lane l of
//    wave s holds candidate j=64s+l's box in registers; uniform t-loop does
//    one broadcast b128 + 1/4-amortized class-byte read; kill bits via
//    __ballot; KILL rows staged per-lane, stored 64-at-a-time. Replaces the
//    3-LDS-gathers-per-(t,i) loop that caused R13's 117K bank conflicts.
//
// ws: keys u64[B*P] = 8,941,568 B

typedef unsigned long long u64;

#define BATCH 128
#define NPRIOR 8732
#define NCLS 21
#define TOPK 200
#define T 1024
#define TARGET 256
#define CAP 384
#define NBIN 4096
#define KW 6
#define NCHUNK 9  // ceil(NPRIOR / T); last chunk = 540 rows

__device__ __forceinline__ double exp_fast(double x) {
  // exp for |x| < ~50, rel err < 1e-14. 2^n via exact bit-built multiply.
  // Bit-identical to the version validated R3..R14.
  const double LOG2E = 1.4426950408889634;
  const double LN2_HI = 6.93147180369123816490e-01;
  const double LN2_LO = 1.90821492927058770002e-10;
  double n = rint(x * LOG2E);
  double r = fma(-n, LN2_HI, x);
  r = fma(-n, LN2_LO, r);
  double p = 2.505210838544172e-08;
  p = fma(p, r, 2.755731922398589e-07);
  p = fma(p, r, 2.7557319223985893e-06);
  p = fma(p, r, 2.48015873015873e-05);
  p = fma(p, r, 1.984126984126984e-04);
  p = fma(p, r, 1.388888888888889e-03);
  p = fma(p, r, 8.333333333333333e-03);
  p = fma(p, r, 4.1666666666666664e-02);
  p = fma(p, r, 1.6666666666666666e-01);
  p = fma(p, r, 0.5);
  p = fma(p, r, 1.0);
  p = fma(p, r, 1.0);
  double scale = __longlong_as_double(((long long)(1023 + (int)n)) << 52);
  return p * scale;
}

__global__ __launch_bounds__(256) void prep_kernel(
    const float* __restrict__ conf, u64* __restrict__ keys) {
  // grid is exact: 4366*256 == B*P, no bounds check needed.
  const int r = blockIdx.x * 256 + threadIdx.x;
  const float* __restrict__ rp = conf + (long long)r * NCLS;
  float cr[NCLS];
#pragma unroll
  for (int j = 0; j < NCLS; ++j) cr[j] = rp[j];  // 21 independent loads
  float m = cr[0];
#pragma unroll
  for (int j = 1; j < NCLS; ++j) m = fmaxf(m, cr[j]);
  float sum = __expf(cr[0] - m);
  float bestr = cr[1];
  float beste = __expf(cr[1] - m);
  sum += beste;
  int bi = 1;
#pragma unroll
  for (int j = 2; j < NCLS; ++j) {
    float rv = cr[j];
    float ej = __expf(rv - m);
    sum += ej;
    if (rv > bestr) { bestr = rv; bi = j; beste = ej; }  // first-idx ties
  }
  float score = __fdividef(beste, sum);  // approx ok: selection only

  const int p = r % NPRIOR;
  u64 key = 0ULL;
  if (score > 0.01f) {
    // Scores in (0.01,2): u64 bits 63..58 constant -> bits 57..46 monotone.
    key = ((u64)__float_as_uint(score) << 32) |
          ((u64)(16383 - p) << 10) | (u64)(bi - 1);
  }
  keys[r] = key;
}

// Descending cutoff bin over hist[4096] (T=1024 callers): cut[0]=c,
// cut[1]=count in bins>c, cut[2]=count in bins>=c. wtot[16]=grand total.
__device__ __forceinline__ void radix_cut(const int* hist, int tid, int tcap,
                                          int* wtot, int* cut) {
  if (tid == 0) cut[2] = 0;
  const int base = tid * 4;
  const int cs = hist[base] + hist[base + 1] + hist[base + 2] + hist[base + 3];
  const int lane = tid & 63;
  int suf = cs;  // within-wave inclusive suffix sum
#pragma unroll
  for (int off = 1; off < 64; off <<= 1) {
    int v = __shfl_down(suf, off);
    if (lane + off < 64) suf += v;
  }
  if (lane == 0) wtot[tid >> 6] = suf;
  __syncthreads();
  if (tid < 16) {  // wave 0: exclusive suffix over following waves
    int v = wtot[tid];
    int s = v;
#pragma unroll
    for (int off = 1; off < 16; off <<= 1) {
      int o = __shfl_down(s, off);
      if (tid + off < 16) s += o;
    }
    if (tid == 0) wtot[16] = s;  // grand total
    wtot[tid] = s - v;
  }
  __syncthreads();
  const int total = wtot[16];
  if (total > 0) {
    const int target = total < tcap ? total : tcap;
    const int S = suf + wtot[tid >> 6];
    const int Snext = S - cs;
    if (S >= target && Snext < target) {  // unique crossing thread
      int acc = Snext;
      for (int bn = base + 3; bn >= base; --bn) {
        acc += hist[bn];
        if (acc >= target) {
          cut[0] = bn; cut[1] = acc - hist[bn]; cut[2] = acc;
          break;
        }
      }
    }
  }
  __syncthreads();
}

__global__ __launch_bounds__(T) void selnms_kernel(
    const float* __restrict__ loc, const float* __restrict__ conf,
    const float* __restrict__ prior, const u64* __restrict__ keys,
    float* __restrict__ out) {
  // DISTINCT shared arrays (no pool carving -> alias analysis works, R8).
  __shared__ int hist[NBIN];        // 16,384 B
  __shared__ u64 buf[CAP];          //  3,072 B (approx keys, unordered)
  __shared__ u64 ebuf[CAP];         //  3,072 B (exact keys)
  __shared__ u64 buf2[CAP];         //  3,072 B (exact, sorted desc)
  __shared__ float4 cbox[CAP];      //  6,144 B (rank-indexed)
  __shared__ float car[CAP];
  __shared__ int ccl[CAP];
  __shared__ __align__(4) unsigned char cclb[CAP];  // class bytes (kill phase)
  __shared__ u64 KILL[CAP * KW];    // 18,432 B
  __shared__ int wtot[17];
  __shared__ int cut1[3], cut2[3];
  __shared__ u64 Ash[KW], KFsh[KW], ACCsh[KW];
  __shared__ float4 abox[TOPK];
  __shared__ float aar[TOPK];
  __shared__ int acl[TOPK];
  __shared__ int sh_cnt, sh_nA;
  // ~59 KB LDS

  const int tid = threadIdx.x;
  const int b = blockIdx.x;
  const float* confb = conf + (long long)b * (NPRIOR * NCLS);
  const float4* loc4 = ((const float4*)loc) + (long long)b * NPRIOR;
  const float4* pr4 = (const float4*)prior;
  float* outb = out + (long long)b * (TOPK * 6);
  const u64* kb = keys + (long long)b * NPRIOR;

  // ---- load batch keys into registers (single global pass, coalesced) ----
  u64 kreg[NCHUNK];
#pragma unroll
  for (int c = 0; c < NCHUNK; ++c) {
    const int i = c * T + tid;
    kreg[c] = (i < NPRIOR) ? kb[i] : 0ULL;
  }
  if (tid == 0) sh_nA = 0;

  // ---- selection + NMS round loop (R11/R13-validated register scans) ----
  u64 ub = ~0ULL;
  int Mr = 0, total = 0;
  while (true) {
    for (int i = tid; i < NBIN; i += T) hist[i] = 0;
    __syncthreads();
#pragma unroll
    for (int c = 0; c < NCHUNK; ++c) {
      u64 k = kreg[c];
      if (k && k < ub) atomicAdd(&hist[(int)((k >> 46) & 0xFFF)], 1);
    }
    __syncthreads();
    radix_cut(hist, tid, TARGET, wtot, cut1);
    total = wtot[16];
    int M = cut1[2];
    if (M == 0) break;
    const int c1 = cut1[0];
    const int baseA = cut1[1];
    const bool need2 = (M > CAP);
    int c2 = 0;
    if (need2) {  // refine within bin c1 on bits 45..34
      for (int i = tid; i < NBIN; i += T) hist[i] = 0;
      __syncthreads();
#pragma unroll
      for (int c = 0; c < NCHUNK; ++c) {
        u64 k = kreg[c];
        if (k && k < ub && (int)((k >> 46) & 0xFFF) == c1)
          atomicAdd(&hist[(int)((k >> 34) & 0xFFF)], 1);
      }
      __syncthreads();
      const int tcap2 = (total < TARGET ? total : TARGET) - baseA;
      radix_cut(hist, tid, tcap2, wtot, cut2);
      c2 = cut2[0];
      M = baseA + cut2[2];
      if (M > CAP) {  // >=129 keys in one 2^-11 rel f32 window: ~impossible
        int Md = M - hist[c2];
        if (Md > 0) { M = Md; c2 = c2 + 1; } else { M = CAP; }
      }
    }
    if (tid == 0) sh_cnt = 0;
    const u64 ubold = ub;
    ub = need2 ? (((u64)c1 << 46) + ((u64)c2 << 34)) : ((u64)c1 << 46);
    __syncthreads();
    // compact (ballot + 1 LDS atomic/wave); i = c*T+tid mapping as validated.
#pragma unroll
    for (int c = 0; c < NCHUNK; ++c) {
      u64 k = kreg[c];
      bool psel = false;
      if (k && k < ubold) {
        int b1 = (int)((k >> 46) & 0xFFF);
        psel = need2 ? (b1 > c1 || (b1 == c1 && (int)((k >> 34) & 0xFFF) >= c2))
                     : (b1 >= c1);
      }
      u64 mask = __ballot(psel ? 1 : 0);
      if (mask) {
        int lane = tid & 63;
        int leader = __ffsll((unsigned long long)mask) - 1;
        int bpos = 0;
        if (lane == leader) bpos = atomicAdd(&sh_cnt, __popcll(mask));
        bpos = __shfl(bpos, leader);
        if (psel) {
          int pos = bpos + __popcll(mask & ((1ULL << lane) - 1ULL));
          if (pos < CAP) buf[pos] = k;
        }
      }
    }
    __syncthreads();
    Mr = sh_cnt;
    if (Mr > CAP) Mr = CAP;
    if (Mr == 0) break;  // defensive

    // ---- NMS core on buf[0..Mr) ----
    // phase A: exact f64 rescore; loc/prior loads issued early, held in regs
    float4 lreg = make_float4(0.f, 0.f, 0.f, 0.f);
    float4 preg = make_float4(0.f, 0.f, 0.f, 0.f);
    int myp = 0, mycl = 0;
    if (tid < Mr) {
      u64 ak = buf[tid];
      mycl = (int)(ak & 0x1FULL);
      myp = 16383 - (int)((ak >> 10) & 0x3FFFULL);
      lreg = loc4[myp];
      preg = pr4[myp];
      const float* crow = confb + (long long)myp * NCLS;
      float cr[NCLS];
#pragma unroll
      for (int j = 0; j < NCLS; ++j) cr[j] = crow[j];  // independent loads
      double m = (double)cr[0];
#pragma unroll
      for (int j = 1; j < NCLS; ++j) m = fmax(m, (double)cr[j]);
      double sum = 0.0, best = -1.0;
#pragma unroll
      for (int j = 0; j < NCLS; ++j) {
        double ej = exp_fast((double)cr[j] - m);
        sum += ej;
        if (j >= 1 && ej > best) best = ej;  // value only; cl fixed by argmax
      }
      double score = best / sum;
      u64 sb = (u64)__double_as_longlong(score);
      ebuf[tid] = ((sb >> 24) << 24) | ((u64)(16383 - myp) << 10) | (u64)mycl;
    }
    if (tid < KW) { Ash[tid] = 0ULL; KFsh[tid] = 0ULL; }
    __syncthreads();
    const int nA0 = sh_nA;

    // phase B: rank sort on exact keys (unique) + decode own candidate.
    if (tid < Mr) {
      u64 ka = ebuf[tid];
      int ra = 0;
      int i = 0;
      for (; i + 8 <= Mr; i += 8) {
        u64 k0 = ebuf[i], k1 = ebuf[i + 1], k2 = ebuf[i + 2], k3 = ebuf[i + 3];
        u64 k4 = ebuf[i + 4], k5 = ebuf[i + 5], k6 = ebuf[i + 6],
            k7 = ebuf[i + 7];
        ra += (int)(k0 > ka) + (int)(k1 > ka) + (int)(k2 > ka) +
              (int)(k3 > ka) + (int)(k4 > ka) + (int)(k5 > ka) +
              (int)(k6 > ka) + (int)(k7 > ka);
      }
      for (; i < Mr; ++i) ra += (int)(ebuf[i] > ka);
      buf2[ra] = ka;
      // fused decode (bit-identical f64 ops), written at rank position
      double cx = (double)preg.x + (double)lreg.x * 0.1 * (double)preg.z;
      double cy = (double)preg.y + (double)lreg.y * 0.1 * (double)preg.w;
      double w = (double)preg.z * exp_fast((double)lreg.z * 0.2);
      double h = (double)preg.w * exp_fast((double)lreg.w * 0.2);
      float x1 = (float)(cx - w * 0.5), y1 = (float)(cy - h * 0.5);
      float x2 = (float)(cx + w * 0.5), y2 = (float)(cy + h * 0.5);
      cbox[ra] = make_float4(x1, y1, x2, y2);
      car[ra] = (x2 - x1) * (y2 - y1);
      ccl[ra] = mycl;
      cclb[ra] = (unsigned char)mycl;
    }
    __syncthreads();

    // pre-round suppression vs already-accepted (rounds >= 2 only)
    if (nA0 > 0 && tid < Mr) {
      const int t = tid;
      float4 my = cbox[t];
      float mar = car[t];
      int mcl = ccl[t];
      bool sup = false;
      for (int a = 0; a < nA0; ++a) {
        if (acl[a] == mcl) {
          float4 ab = abox[a];
          float ix1 = fmaxf(ab.x, my.x), iy1 = fmaxf(ab.y, my.y);
          float ix2 = fminf(ab.z, my.z), iy2 = fminf(ab.w, my.w);
          float inter = fmaxf(ix2 - ix1, 0.f) * fmaxf(iy2 - iy1, 0.f);
          if (inter > 0.45f * (aar[a] + mar - inter)) sup = true;
        }
      }
      if (sup) atomicOr(&Ash[t >> 6], 1ULL << (t & 63));
    }
    // ---- BALLOT kill-mask (R14-validated): wave s owns segment s ----
    {
      const int wv = tid >> 6;
      const int lane = tid & 63;
      if (wv < KW) {
        const int s = wv;
        const int j = s * 64 + lane;
        float4 ob = make_float4(0.f, 0.f, 0.f, 0.f);
        float oar = 0.f;
        int ocl = -1;
        if (j < Mr) { ob = cbox[j]; oar = car[j]; ocl = ccl[j]; }
        // process t in tiles of 64; lane l stages the row word for t=t0+l
        for (int t0 = 0; t0 < Mr; t0 += 64) {
          u64 myrow = 0ULL;
          const int tend = (t0 + 64 < Mr) ? (t0 + 64) : Mr;
          unsigned cw = 0;
          for (int t = t0; t < tend; ++t) {
            if ((t & 3) == 0) cw = *(const unsigned*)&cclb[t & ~3];
            const int clt = (int)((cw >> ((t & 3) * 8)) & 0xFF);
            float4 tb = cbox[t];  // broadcast b128, conflict-free
            bool kill = false;
            if (j > t && j < Mr && clt == ocl) {
              float tar = (tb.z - tb.x) * (tb.w - tb.y);  // == car[t] bitwise
              float ix1 = fmaxf(tb.x, ob.x), iy1 = fmaxf(tb.y, ob.y);
              float ix2 = fminf(tb.z, ob.z), iy2 = fminf(tb.w, ob.w);
              float inter = fmaxf(ix2 - ix1, 0.f) * fmaxf(iy2 - iy1, 0.f);
              kill = inter > 0.45f * (tar + oar - inter);
            }
            u64 mm = __ballot(kill ? 1 : 0);
            if (lane == (t - t0)) myrow = mm;  // stage row for t
          }
          // one strided store: lane l writes KILL[(t0+l)*KW + s]
          if (t0 + lane < Mr) KILL[(t0 + lane) * KW + s] = myrow;
          u64 kf = __ballot(myrow != 0ULL);
          if (lane == 0 && kf) atomicOr(&KFsh[t0 >> 6], kf);
        }
      }
    }
    __syncthreads();
    // uniform serial resolve on wave 0 (validated R5..R14)
    if (tid < 64) {
      u64 A0, A1, A2, A3, A4, A5;
      {
        u64 v[KW];
#pragma unroll
        for (int w = 0; w < KW; ++w) {
          int rem = Mr - 64 * w;
          u64 vm =
              (rem >= 64) ? ~0ULL : (rem <= 0 ? 0ULL : ((1ULL << rem) - 1ULL));
          v[w] = vm & ~Ash[w];
        }
        A0 = v[0]; A1 = v[1]; A2 = v[2]; A3 = v[3]; A4 = v[4]; A5 = v[5];
      }
      u64 C0 = 0, C1 = 0, C2 = 0, C3 = 0, C4 = 0, C5 = 0;
      int nacc = nA0;
      bool full = false;
#define KILLUPD(cidx) do { const u64* kc = &KILL[(cidx) * KW];      \
      A0 &= ~kc[0]; A1 &= ~kc[1]; A2 &= ~kc[2];                     \
      A3 &= ~kc[3]; A4 &= ~kc[4]; A5 &= ~kc[5]; } while (0)
#define RESW(w, Aw, Cw) if (!full) {                                \
      const u64 KFw = KFsh[w];                                      \
      int lim = Mr - (w) * 64; if (lim > 64) lim = 64;              \
      for (int q = 0; q < lim; ++q) {                               \
        if ((Aw >> q) & 1ULL) {                                     \
          Cw |= 1ULL << q; ++nacc;                                  \
          if (nacc == TOPK) { full = true; break; }                 \
          if ((KFw >> q) & 1ULL) KILLUPD((w) * 64 + q);             \
        } } }
      RESW(0, A0, C0)
      RESW(1, A1, C1)
      RESW(2, A2, C2)
      RESW(3, A3, C3)
      RESW(4, A4, C4)
      RESW(5, A5, C5)
#undef RESW
#undef KILLUPD
      if (tid == 0) {
        ACCsh[0] = C0; ACCsh[1] = C1; ACCsh[2] = C2;
        ACCsh[3] = C3; ACCsh[4] = C4; ACCsh[5] = C5;
        sh_nA = nacc;
      }
    }
    __syncthreads();
    // lane-parallel output of accepted candidates
    if (tid < Mr) {
      const int t = tid;
      const int w = t >> 6, q = t & 63;
      const u64 accw = ACCsh[w];
      if ((accw >> q) & 1ULL) {
        int rank = nA0;
#pragma unroll
        for (int w2 = 0; w2 < KW; ++w2)
          if (w2 < w) rank += __popcll(ACCsh[w2]);
        rank += __popcll(accw & ((q == 0) ? 0ULL : ((1ULL << q) - 1ULL)));
        float4 bx = cbox[t];
        float sc =
            (float)__longlong_as_double((long long)((buf2[t] >> 24) << 24));
        float* o = outb + rank * 6;
        o[0] = bx.x; o[1] = bx.y; o[2] = bx.z; o[3] = bx.w;
        o[4] = sc; o[5] = (float)ccl[t];
        abox[rank] = bx; aar[rank] = car[t]; acl[rank] = ccl[t];
      }
    }
    __syncthreads();
    if (sh_nA >= TOPK) break;
    if (total - Mr <= 0) break;  // pool exhausted
  }
  __syncthreads();
  // zero-fill rows [nA, TOPK)
  const int nAf = sh_nA;
  for (int i = nAf * 6 + tid; i < TOPK * 6; i += T) outb[i] = 0.0f;
}

extern "C" void kernel_launch(void* const* d_in, const int* in_sizes, int n_in,
                              void* d_out, int out_size, void* d_ws,
                              size_t ws_size, hipStream_t stream) {
  const float* loc = (const float*)d_in[0];    // B*P*4
  const float* conf = (const float*)d_in[1];   // B*P*21
  const float* prior = (const float*)d_in[2];  // P*4
  float* out = (float*)d_out;                  // B*200*6

  u64* keys = (u64*)d_ws;  // 8,941,568 B
  const int nrows_blocks = (BATCH * NPRIOR) / 256;  // 4366 exact

  prep_kernel<<<nrows_blocks, 256, 0, stream>>>(conf, keys);
  selnms_kernel<<<BATCH, T, 0, stream>>>(loc, conf, prior, keys, out);
}

// Round 8
// 205.743 us; speedup vs baseline: 1.1329x; 1.1206x over previous
//
#include <hip/hip_runtime.h>

// Detect (SSD post-process). B=128 P=8732 C=21 TOP_K=200 CONF=0.01 NMS=0.45
//
// R16 = R13 (best selnms structure) + __launch_bounds__(1024, 4) on selnms.
//  R13/R15 counters showed selnms WRITE_SIZE = 10.8 MB vs 0.6 MB of output:
//  ~9.4 MB = kreg[9] x 8B x 1024thr x 128blk spilled to scratch (VGPR_Count
//  was 64 -- compiler targeted 2 blocks/CU we never use; grid 128 <= 256 CUs).
//  Every selection scan re-read keys from scratch at L2 latency. (1024, 4)
//  = 4 waves/EU = 1 block/CU -> 128-VGPR cap -> kreg stays in registers.
//  R15's ballot kill-mask REVERTED (62 -> 87us regression: serial
//  broadcast+ballot chain on 6 waves loses to 16-wave gather w/ unroll-4 ILP;
//  bank conflicts proved to come from hist atomics, not the gather).
//
//  prep (4366x256, full chip): one thread = one conf row, 21 floats direct
//    to registers (no LDS, no barrier; R12-validated).
//  selnms (128x1024, one block per batch): batch keys -> kreg[9] (one
//    coalesced pass), R11/R13-validated register-scan selection round loop,
//    R13 NMS core (rescore -> rank sort + fused decode -> gather kill-mask ->
//    resolve -> output).
//
// ws: keys u64[B*P] = 8,941,568 B

typedef unsigned long long u64;

#define BATCH 128
#define NPRIOR 8732
#define NCLS 21
#define TOPK 200
#define T 1024
#define TARGET 256
#define CAP 384
#define NBIN 4096
#define KW 6
#define NCHUNK 9  // ceil(NPRIOR / T); last chunk = 540 rows

__device__ __forceinline__ double exp_fast(double x) {
  // exp for |x| < ~50, rel err < 1e-14. 2^n via exact bit-built multiply.
  // Bit-identical to the version validated R3..R15.
  const double LOG2E = 1.4426950408889634;
  const double LN2_HI = 6.93147180369123816490e-01;
  const double LN2_LO = 1.90821492927058770002e-10;
  double n = rint(x * LOG2E);
  double r = fma(-n, LN2_HI, x);
  r = fma(-n, LN2_LO, r);
  double p = 2.505210838544172e-08;
  p = fma(p, r, 2.755731922398589e-07);
  p = fma(p, r, 2.7557319223985893e-06);
  p = fma(p, r, 2.48015873015873e-05);
  p = fma(p, r, 1.984126984126984e-04);
  p = fma(p, r, 1.388888888888889e-03);
  p = fma(p, r, 8.333333333333333e-03);
  p = fma(p, r, 4.1666666666666664e-02);
  p = fma(p, r, 1.6666666666666666e-01);
  p = fma(p, r, 0.5);
  p = fma(p, r, 1.0);
  p = fma(p, r, 1.0);
  double scale = __longlong_as_double(((long long)(1023 + (int)n)) << 52);
  return p * scale;
}

__global__ __launch_bounds__(256) void prep_kernel(
    const float* __restrict__ conf, u64* __restrict__ keys) {
  // grid is exact: 4366*256 == B*P, no bounds check needed.
  const int r = blockIdx.x * 256 + threadIdx.x;
  const float* __restrict__ rp = conf + (long long)r * NCLS;
  float cr[NCLS];
#pragma unroll
  for (int j = 0; j < NCLS; ++j) cr[j] = rp[j];  // 21 independent loads
  float m = cr[0];
#pragma unroll
  for (int j = 1; j < NCLS; ++j) m = fmaxf(m, cr[j]);
  float sum = __expf(cr[0] - m);
  float bestr = cr[1];
  float beste = __expf(cr[1] - m);
  sum += beste;
  int bi = 1;
#pragma unroll
  for (int j = 2; j < NCLS; ++j) {
    float rv = cr[j];
    float ej = __expf(rv - m);
    sum += ej;
    if (rv > bestr) { bestr = rv; bi = j; beste = ej; }  // first-idx ties
  }
  float score = __fdividef(beste, sum);  // approx ok: selection only

  const int p = r % NPRIOR;
  u64 key = 0ULL;
  if (score > 0.01f) {
    // Scores in (0.01,2): u64 bits 63..58 constant -> bits 57..46 monotone.
    key = ((u64)__float_as_uint(score) << 32) |
          ((u64)(16383 - p) << 10) | (u64)(bi - 1);
  }
  keys[r] = key;
}

// Descending cutoff bin over hist[4096] (T=1024 callers): cut[0]=c,
// cut[1]=count in bins>c, cut[2]=count in bins>=c. wtot[16]=grand total.
__device__ __forceinline__ void radix_cut(const int* hist, int tid, int tcap,
                                          int* wtot, int* cut) {
  if (tid == 0) cut[2] = 0;
  const int base = tid * 4;
  const int cs = hist[base] + hist[base + 1] + hist[base + 2] + hist[base + 3];
  const int lane = tid & 63;
  int suf = cs;  // within-wave inclusive suffix sum
#pragma unroll
  for (int off = 1; off < 64; off <<= 1) {
    int v = __shfl_down(suf, off);
    if (lane + off < 64) suf += v;
  }
  if (lane == 0) wtot[tid >> 6] = suf;
  __syncthreads();
  if (tid < 16) {  // wave 0: exclusive suffix over following waves
    int v = wtot[tid];
    int s = v;
#pragma unroll
    for (int off = 1; off < 16; off <<= 1) {
      int o = __shfl_down(s, off);
      if (tid + off < 16) s += o;
    }
    if (tid == 0) wtot[16] = s;  // grand total
    wtot[tid] = s - v;
  }
  __syncthreads();
  const int total = wtot[16];
  if (total > 0) {
    const int target = total < tcap ? total : tcap;
    const int S = suf + wtot[tid >> 6];
    const int Snext = S - cs;
    if (S >= target && Snext < target) {  // unique crossing thread
      int acc = Snext;
      for (int bn = base + 3; bn >= base; --bn) {
        acc += hist[bn];
        if (acc >= target) {
          cut[0] = bn; cut[1] = acc - hist[bn]; cut[2] = acc;
          break;
        }
      }
    }
  }
  __syncthreads();
}

__global__ __launch_bounds__(T, 4) void selnms_kernel(
    const float* __restrict__ loc, const float* __restrict__ conf,
    const float* __restrict__ prior, const u64* __restrict__ keys,
    float* __restrict__ out) {
  // (T, 4): 16-wave block at 4 waves/EU = 1 block/CU -> 128-VGPR cap.
  // Without it the compiler allocated 64 VGPRs and spilled kreg (9.4 MB of
  // scratch WRITE_SIZE measured in R13/R15). Grid 128 <= 256 CUs, so 1
  // block/CU sacrifices nothing.
  // DISTINCT shared arrays (no pool carving -> alias analysis works, R8).
  __shared__ int hist[NBIN];        // 16,384 B
  __shared__ u64 buf[CAP];          //  3,072 B (approx keys, unordered)
  __shared__ u64 ebuf[CAP];         //  3,072 B (exact keys)
  __shared__ u64 buf2[CAP];         //  3,072 B (exact, sorted desc)
  __shared__ float4 cbox[CAP];      //  6,144 B (rank-indexed)
  __shared__ float car[CAP];
  __shared__ int ccl[CAP];
  __shared__ u64 KILL[CAP * KW];    // 18,432 B
  __shared__ int wtot[17];
  __shared__ int cut1[3], cut2[3];
  __shared__ u64 Ash[KW], KFsh[KW], ACCsh[KW];
  __shared__ float4 abox[TOPK];
  __shared__ float aar[TOPK];
  __shared__ int acl[TOPK];
  __shared__ int sh_cnt, sh_nA;
  // ~58 KB LDS

  const int tid = threadIdx.x;
  const int b = blockIdx.x;
  const float* confb = conf + (long long)b * (NPRIOR * NCLS);
  const float4* loc4 = ((const float4*)loc) + (long long)b * NPRIOR;
  const float4* pr4 = (const float4*)prior;
  float* outb = out + (long long)b * (TOPK * 6);
  const u64* kb = keys + (long long)b * NPRIOR;

  // ---- load batch keys into registers (single global pass, coalesced) ----
  u64 kreg[NCHUNK];
#pragma unroll
  for (int c = 0; c < NCHUNK; ++c) {
    const int i = c * T + tid;
    kreg[c] = (i < NPRIOR) ? kb[i] : 0ULL;
  }
  if (tid == 0) sh_nA = 0;

  // ---- selection + NMS round loop (R11/R13-validated register scans) ----
  u64 ub = ~0ULL;
  int Mr = 0, total = 0;
  while (true) {
    for (int i = tid; i < NBIN; i += T) hist[i] = 0;
    __syncthreads();
#pragma unroll
    for (int c = 0; c < NCHUNK; ++c) {
      u64 k = kreg[c];
      if (k && k < ub) atomicAdd(&hist[(int)((k >> 46) & 0xFFF)], 1);
    }
    __syncthreads();
    radix_cut(hist, tid, TARGET, wtot, cut1);
    total = wtot[16];
    int M = cut1[2];
    if (M == 0) break;
    const int c1 = cut1[0];
    const int baseA = cut1[1];
    const bool need2 = (M > CAP);
    int c2 = 0;
    if (need2) {  // refine within bin c1 on bits 45..34
      for (int i = tid; i < NBIN; i += T) hist[i] = 0;
      __syncthreads();
#pragma unroll
      for (int c = 0; c < NCHUNK; ++c) {
        u64 k = kreg[c];
        if (k && k < ub && (int)((k >> 46) & 0xFFF) == c1)
          atomicAdd(&hist[(int)((k >> 34) & 0xFFF)], 1);
      }
      __syncthreads();
      const int tcap2 = (total < TARGET ? total : TARGET) - baseA;
      radix_cut(hist, tid, tcap2, wtot, cut2);
      c2 = cut2[0];
      M = baseA + cut2[2];
      if (M > CAP) {  // >=129 keys in one 2^-11 rel f32 window: ~impossible
        int Md = M - hist[c2];
        if (Md > 0) { M = Md; c2 = c2 + 1; } else { M = CAP; }
      }
    }
    if (tid == 0) sh_cnt = 0;
    const u64 ubold = ub;
    ub = need2 ? (((u64)c1 << 46) + ((u64)c2 << 34)) : ((u64)c1 << 46);
    __syncthreads();
    // compact (ballot + 1 LDS atomic/wave); i = c*T+tid mapping as validated.
#pragma unroll
    for (int c = 0; c < NCHUNK; ++c) {
      u64 k = kreg[c];
      bool psel = false;
      if (k && k < ubold) {
        int b1 = (int)((k >> 46) & 0xFFF);
        psel = need2 ? (b1 > c1 || (b1 == c1 && (int)((k >> 34) & 0xFFF) >= c2))
                     : (b1 >= c1);
      }
      u64 mask = __ballot(psel ? 1 : 0);
      if (mask) {
        int lane = tid & 63;
        int leader = __ffsll((unsigned long long)mask) - 1;
        int bpos = 0;
        if (lane == leader) bpos = atomicAdd(&sh_cnt, __popcll(mask));
        bpos = __shfl(bpos, leader);
        if (psel) {
          int pos = bpos + __popcll(mask & ((1ULL << lane) - 1ULL));
          if (pos < CAP) buf[pos] = k;
        }
      }
    }
    __syncthreads();
    Mr = sh_cnt;
    if (Mr > CAP) Mr = CAP;
    if (Mr == 0) break;  // defensive

    // ---- NMS core on buf[0..Mr) (verbatim R13) ----
    // phase A: exact f64 rescore; loc/prior loads issued early, held in regs
    float4 lreg = make_float4(0.f, 0.f, 0.f, 0.f);
    float4 preg = make_float4(0.f, 0.f, 0.f, 0.f);
    int myp = 0, mycl = 0;
    if (tid < Mr) {
      u64 ak = buf[tid];
      mycl = (int)(ak & 0x1FULL);
      myp = 16383 - (int)((ak >> 10) & 0x3FFFULL);
      lreg = loc4[myp];
      preg = pr4[myp];
      const float* crow = confb + (long long)myp * NCLS;
      float cr[NCLS];
#pragma unroll
      for (int j = 0; j < NCLS; ++j) cr[j] = crow[j];  // independent loads
      double m = (double)cr[0];
#pragma unroll
      for (int j = 1; j < NCLS; ++j) m = fmax(m, (double)cr[j]);
      double sum = 0.0, best = -1.0;
#pragma unroll
      for (int j = 0; j < NCLS; ++j) {
        double ej = exp_fast((double)cr[j] - m);
        sum += ej;
        if (j >= 1 && ej > best) best = ej;  // value only; cl fixed by argmax
      }
      double score = best / sum;
      u64 sb = (u64)__double_as_longlong(score);
      ebuf[tid] = ((sb >> 24) << 24) | ((u64)(16383 - myp) << 10) | (u64)mycl;
    }
    if (tid < KW) { Ash[tid] = 0ULL; KFsh[tid] = 0ULL; }
    __syncthreads();
    const int nA0 = sh_nA;

    // phase B: rank sort on exact keys (unique) + decode own candidate.
    if (tid < Mr) {
      u64 ka = ebuf[tid];
      int ra = 0;
      int i = 0;
      for (; i + 8 <= Mr; i += 8) {
        u64 k0 = ebuf[i], k1 = ebuf[i + 1], k2 = ebuf[i + 2], k3 = ebuf[i + 3];
        u64 k4 = ebuf[i + 4], k5 = ebuf[i + 5], k6 = ebuf[i + 6],
            k7 = ebuf[i + 7];
        ra += (int)(k0 > ka) + (int)(k1 > ka) + (int)(k2 > ka) +
              (int)(k3 > ka) + (int)(k4 > ka) + (int)(k5 > ka) +
              (int)(k6 > ka) + (int)(k7 > ka);
      }
      for (; i < Mr; ++i) ra += (int)(ebuf[i] > ka);
      buf2[ra] = ka;
      // fused decode (bit-identical f64 ops), written at rank position
      double cx = (double)preg.x + (double)lreg.x * 0.1 * (double)preg.z;
      double cy = (double)preg.y + (double)lreg.y * 0.1 * (double)preg.w;
      double w = (double)preg.z * exp_fast((double)lreg.z * 0.2);
      double h = (double)preg.w * exp_fast((double)lreg.w * 0.2);
      float x1 = (float)(cx - w * 0.5), y1 = (float)(cy - h * 0.5);
      float x2 = (float)(cx + w * 0.5), y2 = (float)(cy + h * 0.5);
      cbox[ra] = make_float4(x1, y1, x2, y2);
      car[ra] = (x2 - x1) * (y2 - y1);
      ccl[ra] = mycl;
    }
    __syncthreads();

    // pre-round suppression vs already-accepted (rounds >= 2 only)
    if (nA0 > 0 && tid < Mr) {
      const int t = tid;
      float4 my = cbox[t];
      float mar = car[t];
      int mcl = ccl[t];
      bool sup = false;
      for (int a = 0; a < nA0; ++a) {
        if (acl[a] == mcl) {
          float4 ab = abox[a];
          float ix1 = fmaxf(ab.x, my.x), iy1 = fmaxf(ab.y, my.y);
          float ix2 = fminf(ab.z, my.z), iy2 = fminf(ab.w, my.w);
          float inter = fmaxf(ix2 - ix1, 0.f) * fmaxf(iy2 - iy1, 0.f);
          if (inter > 0.45f * (aar[a] + mar - inter)) sup = true;
        }
      }
      if (sup) atomicOr(&Ash[t >> 6], 1ULL << (t & 63));
    }
    // kill-mask matrix over (candidate t, 64-wide segment) -- R13 gather form
    for (int idx = tid; idx < KW * 512; idx += T) {
      const int seg = idx >> 9;
      const int t = idx & 511;
      if (t < Mr) {
        const int i0 = seg * 64;
        int i1 = i0 + 64;
        if (i1 > Mr) i1 = Mr;
        u64 mm = 0ULL;
        if (i1 > t) {
          float4 my = cbox[t];
          float mar = car[t];
          int mcl = ccl[t];
          int is = (i0 > t + 1) ? i0 : (t + 1);
#pragma unroll 4
          for (int i = is; i < i1; ++i) {
            if (ccl[i] == mcl) {
              float4 cb = cbox[i];
              float ix1 = fmaxf(my.x, cb.x), iy1 = fmaxf(my.y, cb.y);
              float ix2 = fminf(my.z, cb.z), iy2 = fminf(my.w, cb.w);
              float inter = fmaxf(ix2 - ix1, 0.f) * fmaxf(iy2 - iy1, 0.f);
              if (inter > 0.45f * (mar + car[i] - inter))
                mm |= 1ULL << (i - i0);
            }
          }
        }
        KILL[t * KW + seg] = mm;
        if (mm) atomicOr(&KFsh[t >> 6], 1ULL << (t & 63));
      }
    }
    __syncthreads();
    // uniform serial resolve on wave 0 (validated R5..R15)
    if (tid < 64) {
      u64 A0, A1, A2, A3, A4, A5;
      {
        u64 v[KW];
#pragma unroll
        for (int w = 0; w < KW; ++w) {
          int rem = Mr - 64 * w;
          u64 vm =
              (rem >= 64) ? ~0ULL : (rem <= 0 ? 0ULL : ((1ULL << rem) - 1ULL));
          v[w] = vm & ~Ash[w];
        }
        A0 = v[0]; A1 = v[1]; A2 = v[2]; A3 = v[3]; A4 = v[4]; A5 = v[5];
      }
      u64 C0 = 0, C1 = 0, C2 = 0, C3 = 0, C4 = 0, C5 = 0;
      int nacc = nA0;
      bool full = false;
#define KILLUPD(cidx) do { const u64* kc = &KILL[(cidx) * KW];      \
      A0 &= ~kc[0]; A1 &= ~kc[1]; A2 &= ~kc[2];                     \
      A3 &= ~kc[3]; A4 &= ~kc[4]; A5 &= ~kc[5]; } while (0)
#define RESW(w, Aw, Cw) if (!full) {                                \
      const u64 KFw = KFsh[w];                                      \
      int lim = Mr - (w) * 64; if (lim > 64) lim = 64;              \
      for (int q = 0; q < lim; ++q) {                               \
        if ((Aw >> q) & 1ULL) {                                     \
          Cw |= 1ULL << q; ++nacc;                                  \
          if (nacc == TOPK) { full = true; break; }                 \
          if ((KFw >> q) & 1ULL) KILLUPD((w) * 64 + q);             \
        } } }
      RESW(0, A0, C0)
      RESW(1, A1, C1)
      RESW(2, A2, C2)
      RESW(3, A3, C3)
      RESW(4, A4, C4)
      RESW(5, A5, C5)
#undef RESW
#undef KILLUPD
      if (tid == 0) {
        ACCsh[0] = C0; ACCsh[1] = C1; ACCsh[2] = C2;
        ACCsh[3] = C3; ACCsh[4] = C4; ACCsh[5] = C5;
        sh_nA = nacc;
      }
    }
    __syncthreads();
    // lane-parallel output of accepted candidates
    if (tid < Mr) {
      const int t = tid;
      const int w = t >> 6, q = t & 63;
      const u64 accw = ACCsh[w];
      if ((accw >> q) & 1ULL) {
        int rank = nA0;
#pragma unroll
        for (int w2 = 0; w2 < KW; ++w2)
          if (w2 < w) rank += __popcll(ACCsh[w2]);
        rank += __popcll(accw & ((q == 0) ? 0ULL : ((1ULL << q) - 1ULL)));
        float4 bx = cbox[t];
        float sc =
            (float)__longlong_as_double((long long)((buf2[t] >> 24) << 24));
        float* o = outb + rank * 6;
        o[0] = bx.x; o[1] = bx.y; o[2] = bx.z; o[3] = bx.w;
        o[4] = sc; o[5] = (float)ccl[t];
        abox[rank] = bx; aar[rank] = car[t]; acl[rank] = ccl[t];
      }
    }
    __syncthreads();
    if (sh_nA >= TOPK) break;
    if (total - Mr <= 0) break;  // pool exhausted
  }
  __syncthreads();
  // zero-fill rows [nA, TOPK)
  const int nAf = sh_nA;
  for (int i = nAf * 6 + tid; i < TOPK * 6; i += T) outb[i] = 0.0f;
}

extern "C" void kernel_launch(void* const* d_in, const int* in_sizes, int n_in,
                              void* d_out, int out_size, void* d_ws,
                              size_t ws_size, hipStream_t stream) {
  const float* loc = (const float*)d_in[0];    // B*P*4
  const float* conf = (const float*)d_in[1];   // B*P*21
  const float* prior = (const float*)d_in[2];  // P*4
  float* out = (float*)d_out;                  // B*200*6

  u64* keys = (u64*)d_ws;  // 8,941,568 B
  const int nrows_blocks = (BATCH * NPRIOR) / 256;  // 4366 exact

  prep_kernel<<<nrows_blocks, 256, 0, stream>>>(conf, keys);
  selnms_kernel<<<BATCH, T, 0, stream>>>(loc, conf, prior, keys, out);
}

// Round 9
// 186.959 us; speedup vs baseline: 1.2467x; 1.1005x over previous
//
#include <hip/hip_runtime.h>

// Detect (SSD post-process). B=128 P=8732 C=21 TOP_K=200 CONF=0.01 NMS=0.45
//
// R17 = R13 structure, two mechanistic fixes in selnms:
//  (a) CLASS-MASKED kill phase: kills only occur within a class
//      (ccl[i]==mcl gates every IoU). Build CLSM[20][6] presence bitmap
//      (atomicOr in phase B), iterate only set bits. Same-class pairs
//      ~1.7K vs Mr^2/2 ~32K -> the gather phase's ~9.2K wave-level LDS
//      instrs (~35-40us of the 62us, all 16 waves on ONE LDS pipe/CU)
//      collapse ~20x. Kill bits identical: cross-class pairs contribute 0;
//      areas recomputed from stored boxes are bitwise == car[] (R14-proven).
//  (b) keys in LDS Ks[8732] (R8-proven staging) instead of kreg[9]:
//      R13/R16 spilled kreg to scratch (10.8MB WRITE_SIZE vs 0.6MB output;
//      launch_bounds(T,4) did NOT lift the 64-VGPR cap). LDS scans use the
//      exact validated i=tid;i+=T mapping -> bit-identical selection.
//  LDS ~129.3KB -> 1 block/CU (grid 128 <= 256 CUs, free).
//
//  prep (4366x256, full chip): one thread = one conf row, 21 floats direct
//    to registers (no LDS, no barrier; R12-validated). Writes keys.
//
// ws: keys u64[B*P] = 8,941,568 B

typedef unsigned long long u64;

#define BATCH 128
#define NPRIOR 8732
#define NCLS 21
#define TOPK 200
#define T 1024
#define TARGET 256
#define CAP 384
#define NBIN 4096
#define KW 6
#define NCLM 20  // classes 0..19 (bi-1)

__device__ __forceinline__ double exp_fast(double x) {
  // exp for |x| < ~50, rel err < 1e-14. 2^n via exact bit-built multiply.
  // Bit-identical to the version validated R3..R16.
  const double LOG2E = 1.4426950408889634;
  const double LN2_HI = 6.93147180369123816490e-01;
  const double LN2_LO = 1.90821492927058770002e-10;
  double n = rint(x * LOG2E);
  double r = fma(-n, LN2_HI, x);
  r = fma(-n, LN2_LO, r);
  double p = 2.505210838544172e-08;
  p = fma(p, r, 2.755731922398589e-07);
  p = fma(p, r, 2.7557319223985893e-06);
  p = fma(p, r, 2.48015873015873e-05);
  p = fma(p, r, 1.984126984126984e-04);
  p = fma(p, r, 1.388888888888889e-03);
  p = fma(p, r, 8.333333333333333e-03);
  p = fma(p, r, 4.1666666666666664e-02);
  p = fma(p, r, 1.6666666666666666e-01);
  p = fma(p, r, 0.5);
  p = fma(p, r, 1.0);
  p = fma(p, r, 1.0);
  double scale = __longlong_as_double(((long long)(1023 + (int)n)) << 52);
  return p * scale;
}

__global__ __launch_bounds__(256) void prep_kernel(
    const float* __restrict__ conf, u64* __restrict__ keys) {
  // grid is exact: 4366*256 == B*P, no bounds check needed.
  const int r = blockIdx.x * 256 + threadIdx.x;
  const float* __restrict__ rp = conf + (long long)r * NCLS;
  float cr[NCLS];
#pragma unroll
  for (int j = 0; j < NCLS; ++j) cr[j] = rp[j];  // 21 independent loads
  float m = cr[0];
#pragma unroll
  for (int j = 1; j < NCLS; ++j) m = fmaxf(m, cr[j]);
  float sum = __expf(cr[0] - m);
  float bestr = cr[1];
  float beste = __expf(cr[1] - m);
  sum += beste;
  int bi = 1;
#pragma unroll
  for (int j = 2; j < NCLS; ++j) {
    float rv = cr[j];
    float ej = __expf(rv - m);
    sum += ej;
    if (rv > bestr) { bestr = rv; bi = j; beste = ej; }  // first-idx ties
  }
  float score = __fdividef(beste, sum);  // approx ok: selection only

  const int p = r % NPRIOR;
  u64 key = 0ULL;
  if (score > 0.01f) {
    // Scores in (0.01,2): u64 bits 63..58 constant -> bits 57..46 monotone.
    key = ((u64)__float_as_uint(score) << 32) |
          ((u64)(16383 - p) << 10) | (u64)(bi - 1);
  }
  keys[r] = key;
}

// Descending cutoff bin over hist[4096] (T=1024 callers): cut[0]=c,
// cut[1]=count in bins>c, cut[2]=count in bins>=c. wtot[16]=grand total.
__device__ __forceinline__ void radix_cut(const int* hist, int tid, int tcap,
                                          int* wtot, int* cut) {
  if (tid == 0) cut[2] = 0;
  const int base = tid * 4;
  const int cs = hist[base] + hist[base + 1] + hist[base + 2] + hist[base + 3];
  const int lane = tid & 63;
  int suf = cs;  // within-wave inclusive suffix sum
#pragma unroll
  for (int off = 1; off < 64; off <<= 1) {
    int v = __shfl_down(suf, off);
    if (lane + off < 64) suf += v;
  }
  if (lane == 0) wtot[tid >> 6] = suf;
  __syncthreads();
  if (tid < 16) {  // wave 0: exclusive suffix over following waves
    int v = wtot[tid];
    int s = v;
#pragma unroll
    for (int off = 1; off < 16; off <<= 1) {
      int o = __shfl_down(s, off);
      if (tid + off < 16) s += o;
    }
    if (tid == 0) wtot[16] = s;  // grand total
    wtot[tid] = s - v;
  }
  __syncthreads();
  const int total = wtot[16];
  if (total > 0) {
    const int target = total < tcap ? total : tcap;
    const int S = suf + wtot[tid >> 6];
    const int Snext = S - cs;
    if (S >= target && Snext < target) {  // unique crossing thread
      int acc = Snext;
      for (int bn = base + 3; bn >= base; --bn) {
        acc += hist[bn];
        if (acc >= target) {
          cut[0] = bn; cut[1] = acc - hist[bn]; cut[2] = acc;
          break;
        }
      }
    }
  }
  __syncthreads();
}

__global__ __launch_bounds__(T) void selnms_kernel(
    const float* __restrict__ loc, const float* __restrict__ conf,
    const float* __restrict__ prior, const u64* __restrict__ keys,
    float* __restrict__ out) {
  // DISTINCT shared arrays (no pool carving -> alias analysis works, R8).
  __shared__ u64 Ks[NPRIOR];        // 69,856 B (keys; no kreg spill)
  __shared__ int hist[NBIN];        // 16,384 B
  __shared__ u64 buf[CAP];          //  3,072 B (approx keys, unordered)
  __shared__ u64 ebuf[CAP];         //  3,072 B (exact keys)
  __shared__ u64 buf2[CAP];         //  3,072 B (exact, sorted desc)
  __shared__ float4 cbox[CAP];      //  6,144 B (rank-indexed)
  __shared__ float car[CAP];
  __shared__ int ccl[CAP];
  __shared__ u64 KILL[CAP * KW];    // 18,432 B
  __shared__ u64 CLSM[NCLM][KW];    //    960 B (per-class presence bitmap)
  __shared__ int wtot[17];
  __shared__ int cut1[3], cut2[3];
  __shared__ u64 Ash[KW], KFsh[KW], ACCsh[KW];
  __shared__ float4 abox[TOPK];
  __shared__ float aar[TOPK];
  __shared__ int acl[TOPK];
  __shared__ int sh_cnt, sh_nA;
  // ~129.3 KB -> 1 block/CU

  const int tid = threadIdx.x;
  const int b = blockIdx.x;
  const float* confb = conf + (long long)b * (NPRIOR * NCLS);
  const float4* loc4 = ((const float4*)loc) + (long long)b * NPRIOR;
  const float4* pr4 = (const float4*)prior;
  float* outb = out + (long long)b * (TOPK * 6);
  const u64* kb = keys + (long long)b * NPRIOR;

  // ---- stage batch keys into LDS (single coalesced pass; R8-proven) ----
  for (int i = tid; i < NPRIOR; i += T) Ks[i] = kb[i];
  if (tid == 0) sh_nA = 0;
  __syncthreads();

  // ---- selection + NMS round loop (R8-validated LDS scans) ----
  u64 ub = ~0ULL;
  int Mr = 0, total = 0;
  while (true) {
    for (int i = tid; i < NBIN; i += T) hist[i] = 0;
    __syncthreads();
    for (int i = tid; i < NPRIOR; i += T) {
      u64 k = Ks[i];
      if (k && k < ub) atomicAdd(&hist[(int)((k >> 46) & 0xFFF)], 1);
    }
    __syncthreads();
    radix_cut(hist, tid, TARGET, wtot, cut1);
    total = wtot[16];
    int M = cut1[2];
    if (M == 0) break;
    const int c1 = cut1[0];
    const int baseA = cut1[1];
    const bool need2 = (M > CAP);
    int c2 = 0;
    if (need2) {  // refine within bin c1 on bits 45..34
      for (int i = tid; i < NBIN; i += T) hist[i] = 0;
      __syncthreads();
      for (int i = tid; i < NPRIOR; i += T) {
        u64 k = Ks[i];
        if (k && k < ub && (int)((k >> 46) & 0xFFF) == c1)
          atomicAdd(&hist[(int)((k >> 34) & 0xFFF)], 1);
      }
      __syncthreads();
      const int tcap2 = (total < TARGET ? total : TARGET) - baseA;
      radix_cut(hist, tid, tcap2, wtot, cut2);
      c2 = cut2[0];
      M = baseA + cut2[2];
      if (M > CAP) {  // >=129 keys in one 2^-11 rel f32 window: ~impossible
        int Md = M - hist[c2];
        if (Md > 0) { M = Md; c2 = c2 + 1; } else { M = CAP; }
      }
    }
    if (tid == 0) sh_cnt = 0;
    const u64 ubold = ub;
    ub = need2 ? (((u64)c1 << 46) + ((u64)c2 << 34)) : ((u64)c1 << 46);
    __syncthreads();
    // compact (ballot + 1 LDS atomic/wave); i=tid;i+=T mapping as validated.
    for (int i = tid; i < NPRIOR; i += T) {
      u64 k = Ks[i];
      bool psel = false;
      if (k && k < ubold) {
        int b1 = (int)((k >> 46) & 0xFFF);
        psel = need2 ? (b1 > c1 || (b1 == c1 && (int)((k >> 34) & 0xFFF) >= c2))
                     : (b1 >= c1);
      }
      u64 mask = __ballot(psel ? 1 : 0);
      if (mask) {
        int lane = tid & 63;
        int leader = __ffsll((unsigned long long)mask) - 1;
        int bpos = 0;
        if (lane == leader) bpos = atomicAdd(&sh_cnt, __popcll(mask));
        bpos = __shfl(bpos, leader);
        if (psel) {
          int pos = bpos + __popcll(mask & ((1ULL << lane) - 1ULL));
          if (pos < CAP) buf[pos] = k;
        }
      }
    }
    __syncthreads();
    Mr = sh_cnt;
    if (Mr > CAP) Mr = CAP;
    if (Mr == 0) break;  // defensive

    // ---- NMS core on buf[0..Mr) ----
    // phase A: exact f64 rescore; loc/prior loads issued early, held in regs
    float4 lreg = make_float4(0.f, 0.f, 0.f, 0.f);
    float4 preg = make_float4(0.f, 0.f, 0.f, 0.f);
    int myp = 0, mycl = 0;
    if (tid < Mr) {
      u64 ak = buf[tid];
      mycl = (int)(ak & 0x1FULL);
      myp = 16383 - (int)((ak >> 10) & 0x3FFFULL);
      lreg = loc4[myp];
      preg = pr4[myp];
      const float* crow = confb + (long long)myp * NCLS;
      float cr[NCLS];
#pragma unroll
      for (int j = 0; j < NCLS; ++j) cr[j] = crow[j];  // independent loads
      double m = (double)cr[0];
#pragma unroll
      for (int j = 1; j < NCLS; ++j) m = fmax(m, (double)cr[j]);
      double sum = 0.0, best = -1.0;
#pragma unroll
      for (int j = 0; j < NCLS; ++j) {
        double ej = exp_fast((double)cr[j] - m);
        sum += ej;
        if (j >= 1 && ej > best) best = ej;  // value only; cl fixed by argmax
      }
      double score = best / sum;
      u64 sb = (u64)__double_as_longlong(score);
      ebuf[tid] = ((sb >> 24) << 24) | ((u64)(16383 - myp) << 10) | (u64)mycl;
    }
    if (tid < KW) { Ash[tid] = 0ULL; KFsh[tid] = 0ULL; }
    if (tid < NCLM * KW) ((u64*)CLSM)[tid] = 0ULL;
    __syncthreads();
    const int nA0 = sh_nA;

    // phase B: rank sort on exact keys (unique) + decode + CLSM build.
    if (tid < Mr) {
      u64 ka = ebuf[tid];
      int ra = 0;
      int i = 0;
      for (; i + 8 <= Mr; i += 8) {
        u64 k0 = ebuf[i], k1 = ebuf[i + 1], k2 = ebuf[i + 2], k3 = ebuf[i + 3];
        u64 k4 = ebuf[i + 4], k5 = ebuf[i + 5], k6 = ebuf[i + 6],
            k7 = ebuf[i + 7];
        ra += (int)(k0 > ka) + (int)(k1 > ka) + (int)(k2 > ka) +
              (int)(k3 > ka) + (int)(k4 > ka) + (int)(k5 > ka) +
              (int)(k6 > ka) + (int)(k7 > ka);
      }
      for (; i < Mr; ++i) ra += (int)(ebuf[i] > ka);
      buf2[ra] = ka;
      // fused decode (bit-identical f64 ops), written at rank position
      double cx = (double)preg.x + (double)lreg.x * 0.1 * (double)preg.z;
      double cy = (double)preg.y + (double)lreg.y * 0.1 * (double)preg.w;
      double w = (double)preg.z * exp_fast((double)lreg.z * 0.2);
      double h = (double)preg.w * exp_fast((double)lreg.w * 0.2);
      float x1 = (float)(cx - w * 0.5), y1 = (float)(cy - h * 0.5);
      float x2 = (float)(cx + w * 0.5), y2 = (float)(cy + h * 0.5);
      cbox[ra] = make_float4(x1, y1, x2, y2);
      car[ra] = (x2 - x1) * (y2 - y1);
      ccl[ra] = mycl;
      atomicOr(&CLSM[mycl][ra >> 6], 1ULL << (ra & 63));
    }
    __syncthreads();

    // pre-round suppression vs already-accepted (rounds >= 2 only)
    if (nA0 > 0 && tid < Mr) {
      const int t = tid;
      float4 my = cbox[t];
      float mar = car[t];
      int mcl = ccl[t];
      bool sup = false;
      for (int a = 0; a < nA0; ++a) {
        if (acl[a] == mcl) {
          float4 ab = abox[a];
          float ix1 = fmaxf(ab.x, my.x), iy1 = fmaxf(ab.y, my.y);
          float ix2 = fminf(ab.z, my.z), iy2 = fminf(ab.w, my.w);
          float inter = fmaxf(ix2 - ix1, 0.f) * fmaxf(iy2 - iy1, 0.f);
          if (inter > 0.45f * (aar[a] + mar - inter)) sup = true;
        }
      }
      if (sup) atomicOr(&Ash[t >> 6], 1ULL << (t & 63));
    }
    // ---- class-masked kill-mask over (candidate t, 64-wide segment) ----
    // Only same-class candidates can kill: iterate CLSM[mcl][seg] set bits
    // restricted to i > t. Identical kill bits to the full gather (cross-
    // class pairs fail ccl[i]==mcl); areas recomputed from stored boxes are
    // bitwise == car[] (R14-validated: same sub/sub/mul on same floats).
    for (int idx = tid; idx < KW * 512; idx += T) {
      const int seg = idx >> 9;
      const int t = idx & 511;
      if (t < Mr) {
        const int i0 = seg * 64;
        u64 mm = 0ULL;
        u64 cm = CLSM[ccl[t]][seg];
        const int d = t - i0;  // need bits l with l > d (i.e. i > t)
        if (d >= 63) cm = 0ULL;
        else if (d >= 0) cm &= ~((1ULL << (d + 1)) - 1ULL);
        if (cm) {
          const float4 my = cbox[t];
          const float mar = (my.z - my.x) * (my.w - my.y);  // == car[t]
          do {
            const int l = __ffsll((unsigned long long)cm) - 1;
            cm &= cm - 1ULL;
            const int i = i0 + l;
            const float4 cb = cbox[i];
            const float tar = (cb.z - cb.x) * (cb.w - cb.y);  // == car[i]
            float ix1 = fmaxf(my.x, cb.x), iy1 = fmaxf(my.y, cb.y);
            float ix2 = fminf(my.z, cb.z), iy2 = fminf(my.w, cb.w);
            float inter = fmaxf(ix2 - ix1, 0.f) * fmaxf(iy2 - iy1, 0.f);
            if (inter > 0.45f * (mar + tar - inter)) mm |= 1ULL << l;
          } while (cm);
        }
        KILL[t * KW + seg] = mm;
        if (mm) atomicOr(&KFsh[t >> 6], 1ULL << (t & 63));
      }
    }
    __syncthreads();
    // uniform serial resolve on wave 0 (validated R5..R16)
    if (tid < 64) {
      u64 A0, A1, A2, A3, A4, A5;
      {
        u64 v[KW];
#pragma unroll
        for (int w = 0; w < KW; ++w) {
          int rem = Mr - 64 * w;
          u64 vm =
              (rem >= 64) ? ~0ULL : (rem <= 0 ? 0ULL : ((1ULL << rem) - 1ULL));
          v[w] = vm & ~Ash[w];
        }
        A0 = v[0]; A1 = v[1]; A2 = v[2]; A3 = v[3]; A4 = v[4]; A5 = v[5];
      }
      u64 C0 = 0, C1 = 0, C2 = 0, C3 = 0, C4 = 0, C5 = 0;
      int nacc = nA0;
      bool full = false;
#define KILLUPD(cidx) do { const u64* kc = &KILL[(cidx) * KW];      \
      A0 &= ~kc[0]; A1 &= ~kc[1]; A2 &= ~kc[2];                     \
      A3 &= ~kc[3]; A4 &= ~kc[4]; A5 &= ~kc[5]; } while (0)
#define RESW(w, Aw, Cw) if (!full) {                                \
      const u64 KFw = KFsh[w];                                      \
      int lim = Mr - (w) * 64; if (lim > 64) lim = 64;              \
      for (int q = 0; q < lim; ++q) {                               \
        if ((Aw >> q) & 1ULL) {                                     \
          Cw |= 1ULL << q; ++nacc;                                  \
          if (nacc == TOPK) { full = true; break; }                 \
          if ((KFw >> q) & 1ULL) KILLUPD((w) * 64 + q);             \
        } } }
      RESW(0, A0, C0)
      RESW(1, A1, C1)
      RESW(2, A2, C2)
      RESW(3, A3, C3)
      RESW(4, A4, C4)
      RESW(5, A5, C5)
#undef RESW
#undef KILLUPD
      if (tid == 0) {
        ACCsh[0] = C0; ACCsh[1] = C1; ACCsh[2] = C2;
        ACCsh[3] = C3; ACCsh[4] = C4; ACCsh[5] = C5;
        sh_nA = nacc;
      }
    }
    __syncthreads();
    // lane-parallel output of accepted candidates
    if (tid < Mr) {
      const int t = tid;
      const int w = t >> 6, q = t & 63;
      const u64 accw = ACCsh[w];
      if ((accw >> q) & 1ULL) {
        int rank = nA0;
#pragma unroll
        for (int w2 = 0; w2 < KW; ++w2)
          if (w2 < w) rank += __popcll(ACCsh[w2]);
        rank += __popcll(accw & ((q == 0) ? 0ULL : ((1ULL << q) - 1ULL)));
        float4 bx = cbox[t];
        float sc =
            (float)__longlong_as_double((long long)((buf2[t] >> 24) << 24));
        float* o = outb + rank * 6;
        o[0] = bx.x; o[1] = bx.y; o[2] = bx.z; o[3] = bx.w;
        o[4] = sc; o[5] = (float)ccl[t];
        abox[rank] = bx; aar[rank] = car[t]; acl[rank] = ccl[t];
      }
    }
    __syncthreads();
    if (sh_nA >= TOPK) break;
    if (total - Mr <= 0) break;  // pool exhausted
  }
  __syncthreads();
  // zero-fill rows [nA, TOPK)
  const int nAf = sh_nA;
  for (int i = nAf * 6 + tid; i < TOPK * 6; i += T) outb[i] = 0.0f;
}

extern "C" void kernel_launch(void* const* d_in, const int* in_sizes, int n_in,
                              void* d_out, int out_size, void* d_ws,
                              size_t ws_size, hipStream_t stream) {
  const float* loc = (const float*)d_in[0];    // B*P*4
  const float* conf = (const float*)d_in[1];   // B*P*21
  const float* prior = (const float*)d_in[2];  // P*4
  float* out = (float*)d_out;                  // B*200*6

  u64* keys = (u64*)d_ws;  // 8,941,568 B
  const int nrows_blocks = (BATCH * NPRIOR) / 256;  // 4366 exact

  prep_kernel<<<nrows_blocks, 256, 0, stream>>>(conf, keys);
  selnms_kernel<<<BATCH, T, 0, stream>>>(loc, conf, prior, keys, out);
}